// Round 13
// baseline (535.694 us; speedup 1.0000x reference)
//
#include <hip/hip_runtime.h>
#include <hip/hip_bf16.h>
#include <cstdint>
#include <cstddef>

// ---------------------------------------------------------------------------
// FlowformerLayer: LN1 -> flow-attention(batch0) -> +res -> LN2 -> MLP -> +res
// B=2, L=16384, D=512, H=8, DH=64, F=2048
// GEMMs: gemmW 256x128 block tile, wave tile 128x64 (8x4 fragments) — raises
//   register-level reuse from 32.8 to 43.7 FLOP per LDS byte. R12 analysis:
//   every prior structure moved 192KB LDS per 4.2 MFLOP per CU -> ~1500cy at
//   measured ds_read_b128 throughput ~= the observed 1250cy/K-tile -> the
//   20% MfmaUtil plateau is LDS-BW-bound. Same R12 sync skeleton (BK=32,
//   dbuf 48KB, 1 barrier/K-tile, WAITV(0)), 2 blocks/CU.
// sa stored bf16 (Wo epilogue + x2ln2 read) — saves ~130MB traffic.
// prep_k: fused weight transposes + biascat + zeroing (1 launch).
// Attention: 3 passes over bf16 q/k/v, slab-reduced (no contended atomics).
// ---------------------------------------------------------------------------

#define L_SEQ 16384
#define EPSF 1e-6f

typedef __bf16 b16x8 __attribute__((ext_vector_type(8)));
typedef __bf16 b16x4 __attribute__((ext_vector_type(4)));
typedef float  f32x4 __attribute__((ext_vector_type(4)));

#define FENCE() asm volatile("" ::: "memory")
#define BARF()  { FENCE(); __builtin_amdgcn_s_barrier(); FENCE(); }
#define WAITV(n) asm volatile("s_waitcnt vmcnt(" #n ")" ::: "memory")

__device__ __forceinline__ void gload16(const void* g, void* l) {
  __builtin_amdgcn_global_load_lds((const __attribute__((address_space(1))) void*)g,
                                   (__attribute__((address_space(3))) void*)l, 16, 0, 0);
}

__device__ __forceinline__ float sigmoidf_(float x) { return 1.f / (1.f + __expf(-x)); }

// ---------------- prep: all weight transposes + biascat + zeroing, 1 launch
__global__ __launch_bounds__(256) void prep_k(const float* __restrict__ Wq,
                                              const float* __restrict__ Wk,
                                              const float* __restrict__ Wv,
                                              const float* __restrict__ Wo,
                                              const float* __restrict__ W1,
                                              const float* __restrict__ W2,
                                              const float* __restrict__ bq,
                                              const float* __restrict__ bk,
                                              const float* __restrict__ bv,
                                              __bf16* __restrict__ Wqkvt,
                                              __bf16* __restrict__ Wot,
                                              __bf16* __restrict__ W1t,
                                              __bf16* __restrict__ W2t,
                                              float* __restrict__ biascat,
                                              float* __restrict__ zstats) {
  const int b = blockIdx.x;
  if (b >= 3072) {
    const int i = (b - 3072) * 256 + threadIdx.x;
    if (i < 1536) biascat[i] = (i < 512) ? bq[i] : (i < 1024) ? bk[i - 512] : bv[i - 1024];
    else if (i < 1536 + 2112) zstats[i - 1536] = 0.f;
    return;
  }
  const float* src;
  __bf16* dst;
  int K, N, bx, by;
  if (b < 256)       { src = Wq; dst = Wqkvt;                      K = 512;  N = 512;  const int r = b;        bx = r & 15; by = r >> 4; }
  else if (b < 512)  { src = Wk; dst = Wqkvt + (size_t)512 * 512;  K = 512;  N = 512;  const int r = b - 256;  bx = r & 15; by = r >> 4; }
  else if (b < 768)  { src = Wv; dst = Wqkvt + (size_t)1024 * 512; K = 512;  N = 512;  const int r = b - 512;  bx = r & 15; by = r >> 4; }
  else if (b < 1024) { src = Wo; dst = Wot;                        K = 512;  N = 512;  const int r = b - 768;  bx = r & 15; by = r >> 4; }
  else if (b < 2048) { src = W1; dst = W1t;                        K = 512;  N = 2048; const int r = b - 1024; bx = r & 63; by = r >> 6; }
  else               { src = W2; dst = W2t;                        K = 2048; N = 512;  const int r = b - 2048; bx = r & 15; by = r >> 4; }
  __shared__ float tile[32][33];
  const int k0 = by * 32, n0 = bx * 32;
  const int tx = threadIdx.x & 31, ty = threadIdx.x >> 5;
#pragma unroll
  for (int i = 0; i < 32; i += 8) tile[ty + i][tx] = src[(size_t)(k0 + ty + i) * N + n0 + tx];
  __syncthreads();
#pragma unroll
  for (int i = 0; i < 32; i += 8)
    dst[(size_t)(n0 + ty + i) * K + k0 + tx] = (__bf16)tile[tx][ty + i];
}

// ---------------- LayerNorm over D=512, one row per block
__global__ __launch_bounds__(128) void ln_rows(const float* __restrict__ x,
                                               const float* __restrict__ g,
                                               const float* __restrict__ be,
                                               __bf16* __restrict__ out) {
  const int row = blockIdx.x, t = threadIdx.x;
  const float4 xv = reinterpret_cast<const float4*>(x + (size_t)row * 512)[t];
  float s = xv.x + xv.y + xv.z + xv.w;
  float s2 = xv.x * xv.x + xv.y * xv.y + xv.z * xv.z + xv.w * xv.w;
#pragma unroll
  for (int off = 32; off > 0; off >>= 1) { s += __shfl_down(s, off); s2 += __shfl_down(s2, off); }
  __shared__ float red[4];
  if ((t & 63) == 0) { red[(t >> 6) * 2] = s; red[(t >> 6) * 2 + 1] = s2; }
  __syncthreads();
  const float S = red[0] + red[2], S2 = red[1] + red[3];
  const float mean = S * (1.f / 512.f);
  const float var = S2 * (1.f / 512.f) - mean * mean;
  const float inv = rsqrtf(var + 1e-5f);
  const float4 gv = reinterpret_cast<const float4*>(g)[t];
  const float4 bv = reinterpret_cast<const float4*>(be)[t];
  b16x4 o;
  o[0] = (__bf16)((xv.x - mean) * inv * gv.x + bv.x);
  o[1] = (__bf16)((xv.y - mean) * inv * gv.y + bv.y);
  o[2] = (__bf16)((xv.z - mean) * inv * gv.z + bv.z);
  o[3] = (__bf16)((xv.w - mean) * inv * gv.w + bv.w);
  reinterpret_cast<b16x4*>(out + (size_t)row * 512)[t] = o;
}

// ---------------- x2 = x + sa0 + sa1 + bo (sa bf16); d_out=x2; ln2=LN(x2)
__global__ __launch_bounds__(128) void x2ln2_k(const float* __restrict__ x,
                                               const __bf16* __restrict__ sa0,
                                               const __bf16* __restrict__ sa1,
                                               const float* __restrict__ bo,
                                               const float* __restrict__ g,
                                               const float* __restrict__ be,
                                               float* __restrict__ xout,
                                               __bf16* __restrict__ lnout) {
  const int row = blockIdx.x, t = threadIdx.x;
  const int l = row & (L_SEQ - 1);
  float4 xv = reinterpret_cast<const float4*>(x + (size_t)row * 512)[t];
  const b16x4 s0 = reinterpret_cast<const b16x4*>(sa0 + (size_t)l * 512)[t];
  const b16x4 s1 = reinterpret_cast<const b16x4*>(sa1 + (size_t)l * 512)[t];
  const float4 bb = reinterpret_cast<const float4*>(bo)[t];
  xv.x += (float)s0[0] + (float)s1[0] + bb.x;
  xv.y += (float)s0[1] + (float)s1[1] + bb.y;
  xv.z += (float)s0[2] + (float)s1[2] + bb.z;
  xv.w += (float)s0[3] + (float)s1[3] + bb.w;
  reinterpret_cast<float4*>(xout + (size_t)row * 512)[t] = xv;
  float s = xv.x + xv.y + xv.z + xv.w;
  float s2 = xv.x * xv.x + xv.y * xv.y + xv.z * xv.z + xv.w * xv.w;
#pragma unroll
  for (int off = 32; off > 0; off >>= 1) { s += __shfl_down(s, off); s2 += __shfl_down(s2, off); }
  __shared__ float red[4];
  if ((t & 63) == 0) { red[(t >> 6) * 2] = s; red[(t >> 6) * 2 + 1] = s2; }
  __syncthreads();
  const float S = red[0] + red[2], S2 = red[1] + red[3];
  const float mean = S * (1.f / 512.f);
  const float var = S2 * (1.f / 512.f) - mean * mean;
  const float inv = rsqrtf(var + 1e-5f);
  const float4 gv = reinterpret_cast<const float4*>(g)[t];
  const float4 bv = reinterpret_cast<const float4*>(be)[t];
  b16x4 o;
  o[0] = (__bf16)((xv.x - mean) * inv * gv.x + bv.x);
  o[1] = (__bf16)((xv.y - mean) * inv * gv.y + bv.y);
  o[2] = (__bf16)((xv.z - mean) * inv * gv.z + bv.z);
  o[3] = (__bf16)((xv.w - mean) * inv * gv.w + bv.w);
  reinterpret_cast<b16x4*>(lnout + (size_t)row * 512)[t] = o;
}

// ---------------- gemmW: 256x128 block tile, wave tile 128x64 (8x4 frags) --
// LDS per buffer: A 256x32 (16KB) at [0,8192), B 128x32 (8KB) at [8192,12288);
// 2 buffers = 48KB. 6 gload16/K-tile. Reads/K-tile/wave: 8 A + 4 B = 12KB
// for 32 MFMAs -> 43.7 FLOP/B (vs 32.8 in R12's 4x4).
// EPI 0: QKV (+biascat, sigmoid q/k -> bf16 h0/h1 + colsums f1/f2; v -> bf16)
// EPI 1: SA  (val -> bf16 h0, split-K via blockIdx.y)
// EPI 2: GELU(+bias -> bf16 h0, stride N)
// EPI 3: OUT (f0[row,col] += acc + bias)
template <int EPI, int KSPL>
__global__ __launch_bounds__(256, 2) void gemmW(const __bf16* __restrict__ A,
                                                const __bf16* __restrict__ Bt,
                                                const int M, const int N, const int K,
                                                const float* __restrict__ bias,
                                                float* __restrict__ f0,
                                                __bf16* __restrict__ h0,
                                                __bf16* __restrict__ h1,
                                                float* __restrict__ f1,
                                                float* __restrict__ f2) {
  __shared__ alignas(16) __bf16 lds[24576];  // 48 KB

  if constexpr (KSPL) {
    const int z = blockIdx.y;
    A += (size_t)z * (K >> 1);
    Bt += (size_t)z * (K >> 1);
    h0 += (size_t)z * ((size_t)M * N);
  }
  const int nt = KSPL ? (K >> 6) : (K >> 5);

  const int nwg = gridDim.x;
  const int orig = blockIdx.x;
  const int cpx = nwg >> 3;
  const int wg = (orig & 7) * cpx + (orig >> 3);
  const int gx = N >> 7;
  const int bm = (wg / gx) << 8;
  const int bn = (wg % gx) << 7;

  const int t = threadIdx.x;
  const int w = t >> 6, lane = t & 63;
  const int wr = w >> 1, wc = w & 1;   // waves 2x2: wave tile 128x64
  const int fr = lane & 15;
  const int kb = lane >> 4;

  const __bf16* As = A + (size_t)(bm + (t >> 2)) * K + (t & 3) * 8;
  const __bf16* Bs = Bt + (size_t)(bn + (t >> 2)) * K + (t & 3) * 8;

  f32x4 acc[8][4] = {};

  auto STG = [&](int s) {
    const int sel = (s & 1) * 12288;
    const __bf16* ap = As + (s << 5);
    const __bf16* bp = Bs + (s << 5);
    gload16(ap, &lds[sel + t * 8]);
    gload16(ap + (size_t)64 * K, &lds[sel + 2048 + t * 8]);
    gload16(ap + (size_t)128 * K, &lds[sel + 4096 + t * 8]);
    gload16(ap + (size_t)192 * K, &lds[sel + 6144 + t * 8]);
    gload16(bp, &lds[sel + 8192 + t * 8]);
    gload16(bp + (size_t)64 * K, &lds[sel + 8192 + 2048 + t * 8]);
  };

  STG(0);
  WAITV(0);
  BARF();

  for (int s = 0; s < nt; s++) {
    if (s + 1 < nt) STG(s + 1);
    const int ab = (s & 1) * 12288 + (wr * 128 + fr) * 32 + kb * 8;
    const int bb2 = (s & 1) * 12288 + 8192 + (wc * 64 + fr) * 32 + kb * 8;
    b16x8 av[8], bv[4];
#pragma unroll
    for (int m = 0; m < 8; m++)
      av[m] = *reinterpret_cast<const b16x8*>(&lds[ab + m * 512]);
#pragma unroll
    for (int n = 0; n < 4; n++)
      bv[n] = *reinterpret_cast<const b16x8*>(&lds[bb2 + n * 512]);
#pragma unroll
    for (int m = 0; m < 8; m++)
#pragma unroll
      for (int n = 0; n < 4; n++)
        acc[m][n] = __builtin_amdgcn_mfma_f32_16x16x32_bf16(av[m], bv[n], acc[m][n], 0, 0, 0);
    WAITV(0);
    BARF();
  }

  const int r0 = kb * 4;
  const int cc = fr;
  if constexpr (EPI == 0) {
    const int which = bn >> 9;  // 0=q, 1=k, 2=v (bn mult of 128, uniform)
    float cs[4] = {0.f, 0.f, 0.f, 0.f};
#pragma unroll
    for (int m = 0; m < 8; m++) {
#pragma unroll
      for (int n = 0; n < 4; n++) {
        const int col = bn + wc * 64 + n * 16 + cc;
        const int c2 = col & 511;
#pragma unroll
        for (int r = 0; r < 4; r++) {
          const int row = bm + wr * 128 + m * 16 + r0 + r;
          float val = acc[m][n][r] + bias[col];
          if (which < 2) {
            val = sigmoidf_(val);
            cs[n] += val;
            ((which == 0) ? h0 : h1)[(size_t)row * 512 + c2] = (__bf16)val;
          } else {
            f2 ? (void)0 : (void)0;  // silence unused warnings pattern
            ((__bf16*)f0)[(size_t)row * 512 + c2] = (__bf16)val;  // v bf16
          }
        }
      }
    }
    if (which < 2) {
      float* sums = (which == 0) ? f1 : f2;
#pragma unroll
      for (int n = 0; n < 4; n++) {
        float s = cs[n];
        s += __shfl_xor(s, 16);
        s += __shfl_xor(s, 32);
        if (kb == 0) atomicAdd(&sums[(bn & 511) + wc * 64 + n * 16 + cc], s);
      }
    }
  } else {
#pragma unroll
    for (int m = 0; m < 8; m++) {
#pragma unroll
      for (int n = 0; n < 4; n++) {
        const int col = bn + wc * 64 + n * 16 + cc;
#pragma unroll
        for (int r = 0; r < 4; r++) {
          const int row = bm + wr * 128 + m * 16 + r0 + r;
          const float val = acc[m][n][r];
          if constexpr (EPI == 1) {
            h0[(size_t)row * N + col] = (__bf16)val;   // sa bf16
          } else if constexpr (EPI == 2) {
            const float xg = val + bias[col];
            const float gel = 0.5f * xg * (1.f + erff(xg * 0.70710678118f));
            h0[(size_t)row * N + col] = (__bf16)gel;
          } else {
            const size_t idx = (size_t)row * N + col;
            f0[idx] = f0[idx] + val + bias[col];
          }
        }
      }
    }
  }
}

// ---------------- attention pass 1 ------------------------------------------
__global__ __launch_bounds__(256) void attn_pass1(const __bf16* __restrict__ q,
                                                  const __bf16* __restrict__ k,
                                                  const float* __restrict__ qsum,
                                                  const float* __restrict__ ksum,
                                                  float* __restrict__ si_out,
                                                  float* __restrict__ qkpart) {
  __shared__ float lsQ[512], lsK[512];
  const int t = threadIdx.x, lane = t & 63, wv = t >> 6;
  const int c0 = lane * 8;
  lsQ[t] = 0.f; lsQ[t + 256] = 0.f;
  lsK[t] = 0.f; lsK[t + 256] = 0.f;
  __syncthreads();
  float qs[8], ks[8];
#pragma unroll
  for (int j = 0; j < 8; j++) {
    qs[j] = qsum[c0 + j] + EPSF;
    ks[j] = ksum[c0 + j] + EPSF;
  }
  const int h = lane >> 3;
  float qacc[8] = {}, kacc[8] = {};
#pragma unroll 1
  for (int i = 0; i < 8; i++) {
    const int l = blockIdx.x * 32 + wv * 8 + i;
    const b16x8 q8 = *reinterpret_cast<const b16x8*>(q + (size_t)l * 512 + c0);
    const b16x8 k8 = *reinterpret_cast<const b16x8*>(k + (size_t)l * 512 + c0);
    float qf[8], kf[8];
    float p1 = 0.f, p2 = 0.f;
#pragma unroll
    for (int j = 0; j < 8; j++) {
      qf[j] = (float)q8[j]; kf[j] = (float)k8[j];
      p1 += (qf[j] + EPSF) * ks[j];
      p2 += (kf[j] + EPSF) * qs[j];
    }
    p1 += __shfl_xor(p1, 1); p2 += __shfl_xor(p2, 1);
    p1 += __shfl_xor(p1, 2); p2 += __shfl_xor(p2, 2);
    p1 += __shfl_xor(p1, 4); p2 += __shfl_xor(p2, 4);
    const float siv = 1.f / p1, sov = 1.f / p2;
    if ((lane & 7) == 0) si_out[h * L_SEQ + l] = siv;
#pragma unroll
    for (int j = 0; j < 8; j++) { qacc[j] += qf[j] * siv; kacc[j] += kf[j] * sov; }
  }
#pragma unroll
  for (int j = 0; j < 8; j++) {
    atomicAdd(&lsQ[c0 + j], qacc[j]);
    atomicAdd(&lsK[c0 + j], kacc[j]);
  }
  __syncthreads();
  float* qp = qkpart + (size_t)blockIdx.x * 1024;
  qp[t] = lsQ[t];
  qp[t + 256] = lsQ[t + 256];
  qp[t + 512] = lsK[t];
  qp[t + 768] = lsK[t + 256];
}

__global__ __launch_bounds__(256) void reduce_qk(const float* __restrict__ qkpart,
                                                 float* __restrict__ outv) {
  const int i = blockIdx.x * 256 + threadIdx.x;
  float s = 0.f;
#pragma unroll 4
  for (int b = 0; b < 512; b++) s += qkpart[(size_t)b * 1024 + i];
  outv[i] = s;
}

// ---------------- kv partials (bf16 v) --------------------------------------
__global__ __launch_bounds__(256) void kv_part(const __bf16* __restrict__ k,
                                               const __bf16* __restrict__ v,
                                               const float* __restrict__ qsi,
                                               float* __restrict__ kvpart,
                                               float* __restrict__ separt) {
  const int h = blockIdx.y, bx = blockIdx.x, t = threadIdx.x;
  __shared__ float lsK[64 * 68];
  __shared__ float lsV[64 * 68];
  __shared__ float lsRed[256];
  const int r = t >> 2, cq = (t & 3) * 16;
  float qv[16];
#pragma unroll
  for (int j = 0; j < 16; j++) qv[j] = qsi[h * 64 + cq + j] + EPSF;
  const int d = t & 63, mg = t >> 6;
  f32x4 acc4[4] = {};
  float seloc = 0.f;
#pragma unroll 1
  for (int sc = 0; sc < 4; sc++) {
    const int l = bx * 256 + sc * 64 + r;
    __syncthreads();
    const b16x8 k8a = *reinterpret_cast<const b16x8*>(k + (size_t)l * 512 + h * 64 + cq);
    const b16x8 k8b = *reinterpret_cast<const b16x8*>(k + (size_t)l * 512 + h * 64 + cq + 8);
    const b16x8 v8a = *reinterpret_cast<const b16x8*>(v + (size_t)l * 512 + h * 64 + cq);
    const b16x8 v8b = *reinterpret_cast<const b16x8*>(v + (size_t)l * 512 + h * 64 + cq + 8);
    float kf[16], vf[16];
#pragma unroll
    for (int j = 0; j < 8; j++) {
      kf[j] = (float)k8a[j]; kf[8 + j] = (float)k8b[j];
      vf[j] = (float)v8a[j]; vf[8 + j] = (float)v8b[j];
    }
    float p = 0.f;
#pragma unroll
    for (int j = 0; j < 16; j++) p += (kf[j] + EPSF) * qv[j];
    p += __shfl_xor(p, 1);
    p += __shfl_xor(p, 2);
    p = fminf(fmaxf(p, -1.f), 1.f);
    const float ce = __expf(p);
    if ((t & 3) == 0) seloc += ce;
#pragma unroll
    for (int j = 0; j < 16; j++) {
      lsK[r * 68 + cq + j] = kf[j];
      lsV[r * 68 + cq + j] = vf[j] * ce;
    }
    __syncthreads();
    for (int rr = 0; rr < 64; rr++) {
      const float kd = lsK[rr * 68 + d];
      const f32x4* lv = reinterpret_cast<const f32x4*>(&lsV[rr * 68 + mg * 16]);
#pragma unroll
      for (int jj = 0; jj < 4; jj++) acc4[jj] += lv[jj] * kd;
    }
  }
  float* kp = kvpart + ((size_t)h * 64 + bx) * 4096;
#pragma unroll
  for (int jj = 0; jj < 4; jj++)
    *reinterpret_cast<f32x4*>(&kp[d * 64 + mg * 16 + jj * 4]) = acc4[jj];
  lsRed[t] = ((t & 3) == 0) ? seloc : 0.f;
  __syncthreads();
  for (int s2 = 128; s2 > 0; s2 >>= 1) {
    if (t < s2) lsRed[t] += lsRed[t + s2];
    __syncthreads();
  }
  if (t == 0) separt[h * 64 + bx] = lsRed[0];
}

__global__ __launch_bounds__(256) void kv_reduce(const float* __restrict__ kvpart,
                                                 const float* __restrict__ separt,
                                                 float* __restrict__ kvout,
                                                 float* __restrict__ sumexp) {
  const int h = blockIdx.y, t = threadIdx.x;
  const int i = blockIdx.x * 256 + t;
  float s = 0.f;
#pragma unroll 4
  for (int b = 0; b < 64; b++) s += kvpart[((size_t)h * 64 + b) * 4096 + i];
  kvout[h * 4096 + i] = s;
  if (blockIdx.x == 0 && t < 64) {
    float e = separt[h * 64 + t];
#pragma unroll
    for (int off2 = 32; off2 > 0; off2 >>= 1) e += __shfl_down(e, off2);
    if (t == 0) sumexp[h] = e;
  }
}

// ---------------- o kernel ---------------------------------------------------
__global__ __launch_bounds__(256) void o_kernel(const __bf16* __restrict__ q,
                                                const float* __restrict__ kvin,
                                                const float* __restrict__ si,
                                                const float* __restrict__ kso,
                                                const float* __restrict__ sumexp,
                                                __bf16* __restrict__ o) {
  const int h = blockIdx.y;
  const int l0 = blockIdx.x * 32;
  const int t = threadIdx.x;
  __shared__ float lsKV[64 * 64];
  __shared__ float lsQ[32 * 65];
  __shared__ float lsF[32];
  const float Sfac = (float)L_SEQ / sumexp[h];
#pragma unroll
  for (int j = 0; j < 16; j++) lsKV[t + j * 256] = kvin[h * 4096 + t + j * 256];
  const int r = t >> 3, c8 = (t & 7) * 8;
  float ksov[8];
#pragma unroll
  for (int j = 0; j < 8; j++) ksov[j] = kso[h * 64 + c8 + j] + EPSF;
  const b16x8 q8 = *reinterpret_cast<const b16x8*>(q + (size_t)(l0 + r) * 512 + h * 64 + c8);
  float p = 0.f;
#pragma unroll
  for (int j = 0; j < 8; j++) {
    const float qf = (float)q8[j];
    lsQ[r * 65 + c8 + j] = qf;
    p += (qf + EPSF) * ksov[j];
  }
  p += __shfl_xor(p, 1);
  p += __shfl_xor(p, 2);
  p += __shfl_xor(p, 4);
  if ((t & 7) == 0) lsF[r] = sigmoidf_(p) * si[h * L_SEQ + l0 + r] * Sfac;
  __syncthreads();
  const int m = t & 63, rg = t >> 6;
#pragma unroll 1
  for (int i = 0; i < 8; i++) {
    const int rr = rg + i * 4;
    float a = 0.f;
#pragma unroll
    for (int dd = 0; dd < 64; dd++) a += lsQ[rr * 65 + dd] * lsKV[dd * 64 + m];
    o[(size_t)(l0 + rr) * 512 + h * 64 + m] = (__bf16)(a * lsF[rr]);
  }
}

// ---------------------------------------------------------------------------
extern "C" void kernel_launch(void* const* d_in, const int* in_sizes, int n_in,
                              void* d_out, int out_size, void* d_ws, size_t ws_size,
                              hipStream_t stream) {
  const float* x  = (const float*)d_in[0];
  const float* Wq = (const float*)d_in[1];
  const float* bq = (const float*)d_in[2];
  const float* Wk = (const float*)d_in[3];
  const float* bk = (const float*)d_in[4];
  const float* Wv = (const float*)d_in[5];
  const float* bv = (const float*)d_in[6];
  const float* Wo = (const float*)d_in[7];
  const float* bo = (const float*)d_in[8];
  const float* W1 = (const float*)d_in[9];
  const float* b1 = (const float*)d_in[10];
  const float* W2 = (const float*)d_in[11];
  const float* b2 = (const float*)d_in[12];
  const float* g1 = (const float*)d_in[13];
  const float* be1 = (const float*)d_in[14];
  const float* g2 = (const float*)d_in[15];
  const float* be2 = (const float*)d_in[16];
  float* out = (float*)d_out;

  char* ws = (char*)d_ws;
  size_t off = 0;
  auto alloc = [&](size_t bytes) -> char* {
    char* p = ws + off;
    off += (bytes + 255) & ~(size_t)255;
    return p;
  };

  char* regA = alloc(134217728);
  __bf16* ln1  = (__bf16*)regA;
  __bf16* qb16 = (__bf16*)(regA + 16777216);
  __bf16* kb16 = (__bf16*)(regA + 33554432);
  __bf16* vb16 = (__bf16*)(regA + 50331648);
  __bf16* ob   = (__bf16*)(regA + 83886080);
  __bf16* sa   = (__bf16*)regA;                  // 2 x 16.78 MB (bf16 splits)
  __bf16* act  = (__bf16*)regA;

  __bf16* ln2 = (__bf16*)alloc((size_t)32768 * 512 * 2);
  __bf16* Wqkvt = (__bf16*)alloc((size_t)1536 * 512 * 2);
  __bf16* Wot = (__bf16*)alloc((size_t)512 * 512 * 2);
  __bf16* W1t = (__bf16*)alloc((size_t)2048 * 512 * 2);
  __bf16* W2t = (__bf16*)alloc((size_t)512 * 2048 * 2);
  float* biascat = (float*)alloc(1536 * 4);
  float* si = (float*)alloc((size_t)8 * L_SEQ * 4);
  float* stats = (float*)alloc(34880 * 4);
  float* qsum = stats;
  float* ksum = stats + 512;
  float* qsi = stats + 1024;
  float* kso = stats + 1536;
  float* sumexp = stats + 2048;
  float* kvbuf = stats + 2112;
  float* kvpart = (float*)alloc((size_t)8 * 64 * 4096 * 4);
  float* separt = (float*)alloc(512 * 4);
  float* qkpart = (float*)alloc((size_t)512 * 1024 * 4);

  prep_k<<<3087, 256, 0, stream>>>(Wq, Wk, Wv, Wo, W1, W2, bq, bk, bv,
                                   Wqkvt, Wot, W1t, W2t, biascat, stats);

  ln_rows<<<L_SEQ, 128, 0, stream>>>(x, g1, be1, ln1);
  // QKV: M=16384 (64 Mtiles), N=1536 (12 Ntiles) -> 768 blocks
  gemmW<0, 0><<<768, 256, 0, stream>>>(ln1, Wqkvt, L_SEQ, 1536, 512,
                                       biascat, (float*)vb16, qb16, kb16, qsum, ksum);

  attn_pass1<<<512, 256, 0, stream>>>(qb16, kb16, qsum, ksum, si, qkpart);
  reduce_qk<<<4, 256, 0, stream>>>(qkpart, qsi);
  kv_part<<<dim3(64, 8), 256, 0, stream>>>(kb16, vb16, qsi, kvpart, separt);
  kv_reduce<<<dim3(16, 8), 256, 0, stream>>>(kvpart, separt, kvbuf, sumexp);
  o_kernel<<<dim3(L_SEQ / 32, 8), 256, 0, stream>>>(qb16, kvbuf, si, kso, sumexp, ob);

  // Wo: M=16384 (64), N=512 (4) -> 256 blocks x 2 splits; sa bf16
  gemmW<1, 1><<<dim3(256, 2), 256, 0, stream>>>(ob, Wot, L_SEQ, 512, 512,
                                                nullptr, nullptr, sa, nullptr,
                                                nullptr, nullptr);

  x2ln2_k<<<2 * L_SEQ, 128, 0, stream>>>(x, sa, sa + (size_t)L_SEQ * 512, bo,
                                         g2, be2, out, ln2);

  // W1: M=32768 (128), N=2048 (16) -> 2048 blocks
  gemmW<2, 0><<<2048, 256, 0, stream>>>(ln2, W1t, 2 * L_SEQ, 2048, 512,
                                        b1, nullptr, act, nullptr, nullptr, nullptr);
  // W2: M=32768 (128), N=512 (4) -> 512 blocks
  gemmW<3, 0><<<512, 256, 0, stream>>>(act, W2t, 2 * L_SEQ, 512, 2048,
                                       b2, out, nullptr, nullptr, nullptr, nullptr);
}

// Round 14
// 519.989 us; speedup vs baseline: 1.0302x; 1.0302x over previous
//
#include <hip/hip_runtime.h>
#include <hip/hip_bf16.h>
#include <cstdint>
#include <cstddef>

// ---------------------------------------------------------------------------
// FlowformerLayer: LN1 -> flow-attention(batch0) -> +res -> LN2 -> MLP -> +res
// B=2, L=16384, D=512, H=8, DH=64, F=2048
// QKV/Wo: R12 gemm128 (BK=32, dbuf 32KB, 4 blocks/CU) — best measured.
// W1/W2: gemm128b — 128x128, BK=64, 64-elem (128B) LDS rows + R2-verified
//   XOR swizzle slot=c^(r&7) (the ONLY layout that measured 0 conflicts),
//   dbuf 64KB, 2 blocks/CU, 1 barrier/K-tile. Fills the untested matrix cell
//   {zero-conflict layout x multi-block residency}: R6/R12/R13 multi-block
//   kernels all had 4-way conflicts (8.4M/6.3M); R2-R5/R11 zero-conflict
//   kernels were all 1-block/CU. Mutual masking suspected.
// sa stored bf16 (R13-verified); v bf16; slab-reduced attention chain.
// ---------------------------------------------------------------------------

#define L_SEQ 16384
#define EPSF 1e-6f

typedef __bf16 b16x8 __attribute__((ext_vector_type(8)));
typedef __bf16 b16x4 __attribute__((ext_vector_type(4)));
typedef float  f32x4 __attribute__((ext_vector_type(4)));

#define FENCE() asm volatile("" ::: "memory")
#define BARF()  { FENCE(); __builtin_amdgcn_s_barrier(); FENCE(); }
#define WAITV(n) asm volatile("s_waitcnt vmcnt(" #n ")" ::: "memory")

__device__ __forceinline__ void gload16(const void* g, void* l) {
  __builtin_amdgcn_global_load_lds((const __attribute__((address_space(1))) void*)g,
                                   (__attribute__((address_space(3))) void*)l, 16, 0, 0);
}

__device__ __forceinline__ float sigmoidf_(float x) { return 1.f / (1.f + __expf(-x)); }

// ---------------- prep: all weight transposes + biascat + zeroing, 1 launch
__global__ __launch_bounds__(256) void prep_k(const float* __restrict__ Wq,
                                              const float* __restrict__ Wk,
                                              const float* __restrict__ Wv,
                                              const float* __restrict__ Wo,
                                              const float* __restrict__ W1,
                                              const float* __restrict__ W2,
                                              const float* __restrict__ bq,
                                              const float* __restrict__ bk,
                                              const float* __restrict__ bv,
                                              __bf16* __restrict__ Wqkvt,
                                              __bf16* __restrict__ Wot,
                                              __bf16* __restrict__ W1t,
                                              __bf16* __restrict__ W2t,
                                              float* __restrict__ biascat,
                                              float* __restrict__ zstats) {
  const int b = blockIdx.x;
  if (b >= 3072) {
    const int i = (b - 3072) * 256 + threadIdx.x;
    if (i < 1536) biascat[i] = (i < 512) ? bq[i] : (i < 1024) ? bk[i - 512] : bv[i - 1024];
    else if (i < 1536 + 2112) zstats[i - 1536] = 0.f;
    return;
  }
  const float* src;
  __bf16* dst;
  int K, N, bx, by;
  if (b < 256)       { src = Wq; dst = Wqkvt;                      K = 512;  N = 512;  const int r = b;        bx = r & 15; by = r >> 4; }
  else if (b < 512)  { src = Wk; dst = Wqkvt + (size_t)512 * 512;  K = 512;  N = 512;  const int r = b - 256;  bx = r & 15; by = r >> 4; }
  else if (b < 768)  { src = Wv; dst = Wqkvt + (size_t)1024 * 512; K = 512;  N = 512;  const int r = b - 512;  bx = r & 15; by = r >> 4; }
  else if (b < 1024) { src = Wo; dst = Wot;                        K = 512;  N = 512;  const int r = b - 768;  bx = r & 15; by = r >> 4; }
  else if (b < 2048) { src = W1; dst = W1t;                        K = 512;  N = 2048; const int r = b - 1024; bx = r & 63; by = r >> 6; }
  else               { src = W2; dst = W2t;                        K = 2048; N = 512;  const int r = b - 2048; bx = r & 15; by = r >> 4; }
  __shared__ float tile[32][33];
  const int k0 = by * 32, n0 = bx * 32;
  const int tx = threadIdx.x & 31, ty = threadIdx.x >> 5;
#pragma unroll
  for (int i = 0; i < 32; i += 8) tile[ty + i][tx] = src[(size_t)(k0 + ty + i) * N + n0 + tx];
  __syncthreads();
#pragma unroll
  for (int i = 0; i < 32; i += 8)
    dst[(size_t)(n0 + ty + i) * K + k0 + tx] = (__bf16)tile[tx][ty + i];
}

// ---------------- LayerNorm over D=512, one row per block
__global__ __launch_bounds__(128) void ln_rows(const float* __restrict__ x,
                                               const float* __restrict__ g,
                                               const float* __restrict__ be,
                                               __bf16* __restrict__ out) {
  const int row = blockIdx.x, t = threadIdx.x;
  const float4 xv = reinterpret_cast<const float4*>(x + (size_t)row * 512)[t];
  float s = xv.x + xv.y + xv.z + xv.w;
  float s2 = xv.x * xv.x + xv.y * xv.y + xv.z * xv.z + xv.w * xv.w;
#pragma unroll
  for (int off = 32; off > 0; off >>= 1) { s += __shfl_down(s, off); s2 += __shfl_down(s2, off); }
  __shared__ float red[4];
  if ((t & 63) == 0) { red[(t >> 6) * 2] = s; red[(t >> 6) * 2 + 1] = s2; }
  __syncthreads();
  const float S = red[0] + red[2], S2 = red[1] + red[3];
  const float mean = S * (1.f / 512.f);
  const float var = S2 * (1.f / 512.f) - mean * mean;
  const float inv = rsqrtf(var + 1e-5f);
  const float4 gv = reinterpret_cast<const float4*>(g)[t];
  const float4 bv = reinterpret_cast<const float4*>(be)[t];
  b16x4 o;
  o[0] = (__bf16)((xv.x - mean) * inv * gv.x + bv.x);
  o[1] = (__bf16)((xv.y - mean) * inv * gv.y + bv.y);
  o[2] = (__bf16)((xv.z - mean) * inv * gv.z + bv.z);
  o[3] = (__bf16)((xv.w - mean) * inv * gv.w + bv.w);
  reinterpret_cast<b16x4*>(out + (size_t)row * 512)[t] = o;
}

// ---------------- x2 = x + sa0 + sa1 + bo (sa bf16); d_out=x2; ln2=LN(x2)
__global__ __launch_bounds__(128) void x2ln2_k(const float* __restrict__ x,
                                               const __bf16* __restrict__ sa0,
                                               const __bf16* __restrict__ sa1,
                                               const float* __restrict__ bo,
                                               const float* __restrict__ g,
                                               const float* __restrict__ be,
                                               float* __restrict__ xout,
                                               __bf16* __restrict__ lnout) {
  const int row = blockIdx.x, t = threadIdx.x;
  const int l = row & (L_SEQ - 1);
  float4 xv = reinterpret_cast<const float4*>(x + (size_t)row * 512)[t];
  const b16x4 s0 = reinterpret_cast<const b16x4*>(sa0 + (size_t)l * 512)[t];
  const b16x4 s1 = reinterpret_cast<const b16x4*>(sa1 + (size_t)l * 512)[t];
  const float4 bb = reinterpret_cast<const float4*>(bo)[t];
  xv.x += (float)s0[0] + (float)s1[0] + bb.x;
  xv.y += (float)s0[1] + (float)s1[1] + bb.y;
  xv.z += (float)s0[2] + (float)s1[2] + bb.z;
  xv.w += (float)s0[3] + (float)s1[3] + bb.w;
  reinterpret_cast<float4*>(xout + (size_t)row * 512)[t] = xv;
  float s = xv.x + xv.y + xv.z + xv.w;
  float s2 = xv.x * xv.x + xv.y * xv.y + xv.z * xv.z + xv.w * xv.w;
#pragma unroll
  for (int off = 32; off > 0; off >>= 1) { s += __shfl_down(s, off); s2 += __shfl_down(s2, off); }
  __shared__ float red[4];
  if ((t & 63) == 0) { red[(t >> 6) * 2] = s; red[(t >> 6) * 2 + 1] = s2; }
  __syncthreads();
  const float S = red[0] + red[2], S2 = red[1] + red[3];
  const float mean = S * (1.f / 512.f);
  const float var = S2 * (1.f / 512.f) - mean * mean;
  const float inv = rsqrtf(var + 1e-5f);
  const float4 gv = reinterpret_cast<const float4*>(g)[t];
  const float4 bv = reinterpret_cast<const float4*>(be)[t];
  b16x4 o;
  o[0] = (__bf16)((xv.x - mean) * inv * gv.x + bv.x);
  o[1] = (__bf16)((xv.y - mean) * inv * gv.y + bv.y);
  o[2] = (__bf16)((xv.z - mean) * inv * gv.z + bv.z);
  o[3] = (__bf16)((xv.w - mean) * inv * gv.w + bv.w);
  reinterpret_cast<b16x4*>(lnout + (size_t)row * 512)[t] = o;
}

// ---------------- gemm128 (R12 config): QKV + Wo ----------------------------
// EPI 0: QKV (+biascat, sigmoid q/k -> bf16 h0/h1 + colsums f1/f2; v -> bf16)
// EPI 1: SA  (val -> bf16 h0, split-K via blockIdx.y)
template <int EPI, int KSPL>
__global__ __launch_bounds__(256, 4) void gemm128(const __bf16* __restrict__ A,
                                                  const __bf16* __restrict__ Bt,
                                                  const int M, const int N, const int K,
                                                  const float* __restrict__ bias,
                                                  float* __restrict__ f0,
                                                  __bf16* __restrict__ h0,
                                                  __bf16* __restrict__ h1,
                                                  float* __restrict__ f1,
                                                  float* __restrict__ f2) {
  __shared__ alignas(16) __bf16 lds[16384];  // 32 KB

  if constexpr (KSPL) {
    const int z = blockIdx.y;
    A += (size_t)z * (K >> 1);
    Bt += (size_t)z * (K >> 1);
    h0 += (size_t)z * ((size_t)M * N);
  }
  const int nt = KSPL ? (K >> 6) : (K >> 5);

  const int nwg = gridDim.x;
  const int orig = blockIdx.x;
  const int cpx = nwg >> 3;
  const int wg = (orig & 7) * cpx + (orig >> 3);
  const int gx = N >> 7;
  const int bm = (wg / gx) << 7;
  const int bn = (wg % gx) << 7;

  const int t = threadIdx.x;
  const int w = t >> 6, lane = t & 63;
  const int wr = w >> 1, wc = w & 1;
  const int fr = lane & 15;
  const int kb = lane >> 4;

  const __bf16* As = A + (size_t)(bm + (t >> 2)) * K + (t & 3) * 8;
  const __bf16* Bs = Bt + (size_t)(bn + (t >> 2)) * K + (t & 3) * 8;

  f32x4 acc[4][4] = {};

  auto STG = [&](int s) {
    const int sel = (s & 1) * 4096;
    const __bf16* ap = As + (s << 5);
    const __bf16* bp = Bs + (s << 5);
    gload16(ap, &lds[sel + t * 8]);
    gload16(ap + (size_t)64 * K, &lds[sel + 2048 + t * 8]);
    gload16(bp, &lds[8192 + sel + t * 8]);
    gload16(bp + (size_t)64 * K, &lds[8192 + sel + 2048 + t * 8]);
  };

  STG(0);
  WAITV(0);
  BARF();

  for (int s = 0; s < nt; s++) {
    if (s + 1 < nt) STG(s + 1);
    const int ab = (s & 1) * 4096 + (wr * 64 + fr) * 32 + kb * 8;
    const int bb2 = 8192 + (s & 1) * 4096 + (wc * 64 + fr) * 32 + kb * 8;
    b16x8 av[4], bv[4];
#pragma unroll
    for (int m = 0; m < 4; m++)
      av[m] = *reinterpret_cast<const b16x8*>(&lds[ab + m * 512]);
#pragma unroll
    for (int n = 0; n < 4; n++)
      bv[n] = *reinterpret_cast<const b16x8*>(&lds[bb2 + n * 512]);
#pragma unroll
    for (int m = 0; m < 4; m++)
#pragma unroll
      for (int n = 0; n < 4; n++)
        acc[m][n] = __builtin_amdgcn_mfma_f32_16x16x32_bf16(av[m], bv[n], acc[m][n], 0, 0, 0);
    WAITV(0);
    BARF();
  }

  const int r0 = kb * 4;
  const int cc = fr;
  if constexpr (EPI == 0) {
    const int which = bn >> 9;  // 0=q, 1=k, 2=v
    float cs[4] = {0.f, 0.f, 0.f, 0.f};
#pragma unroll
    for (int m = 0; m < 4; m++) {
#pragma unroll
      for (int n = 0; n < 4; n++) {
        const int col = bn + wc * 64 + n * 16 + cc;
        const int c2 = col & 511;
#pragma unroll
        for (int r = 0; r < 4; r++) {
          const int row = bm + wr * 64 + m * 16 + r0 + r;
          float val = acc[m][n][r] + bias[col];
          if (which < 2) {
            val = sigmoidf_(val);
            cs[n] += val;
            ((which == 0) ? h0 : h1)[(size_t)row * 512 + c2] = (__bf16)val;
          } else {
            ((__bf16*)f0)[(size_t)row * 512 + c2] = (__bf16)val;  // v bf16
          }
        }
      }
    }
    if (which < 2) {
      float* sums = (which == 0) ? f1 : f2;
#pragma unroll
      for (int n = 0; n < 4; n++) {
        float s = cs[n];
        s += __shfl_xor(s, 16);
        s += __shfl_xor(s, 32);
        if (kb == 0) atomicAdd(&sums[(bn & 511) + wc * 64 + n * 16 + cc], s);
      }
    }
  } else {
#pragma unroll
    for (int m = 0; m < 4; m++) {
#pragma unroll
      for (int n = 0; n < 4; n++) {
        const int col = bn + wc * 64 + n * 16 + cc;
#pragma unroll
        for (int r = 0; r < 4; r++) {
          const int row = bm + wr * 64 + m * 16 + r0 + r;
          h0[(size_t)row * N + col] = (__bf16)acc[m][n][r];   // sa bf16
        }
      }
    }
  }
}

// ---------------- gemm128b: 128x128, BK=64, zero-conflict swizzle, 2 blk/CU -
// LDS (elems): buf b at b*16384: A [0,8192), B [8192,16384). 128 rows x 64
// elems per region; chunk c of row r at slot c^(r&7) (R2-verified, 0 confl).
// Staging: thread t -> rows (t>>3)+j*32 (j=0..3), slot t&7; source chunk
// (t&7)^((t>>3)&7); dest linear t*8 + j*2048. 8 gload16/K-tile.
// Frags: row = (wr|wc)*64 + m*16 + fr; chunk c = ks*4+kb (ks=0,1);
// slot = c ^ (row&7) = c ^ ((fr)&7)... row&7 = (m*16+fr)&7 = fr&7. 
// EPI 2: GELU(+bias -> bf16 h0, stride N); EPI 3: f0 += acc + bias.
template <int EPI>
__global__ __launch_bounds__(256, 2) void gemm128b(const __bf16* __restrict__ A,
                                                   const __bf16* __restrict__ Bt,
                                                   const int M, const int N, const int K,
                                                   const float* __restrict__ bias,
                                                   float* __restrict__ f0,
                                                   __bf16* __restrict__ h0) {
  __shared__ alignas(16) __bf16 lds[32768];  // 64 KB

  const int nt = K >> 6;

  const int nwg = gridDim.x;
  const int orig = blockIdx.x;
  const int cpx = nwg >> 3;
  const int wg = (orig & 7) * cpx + (orig >> 3);
  const int gx = N >> 7;
  const int bm = (wg / gx) << 7;
  const int bn = (wg % gx) << 7;

  const int t = threadIdx.x;
  const int w = t >> 6, lane = t & 63;
  const int wr = w >> 1, wc = w & 1;
  const int fr = lane & 15;
  const int kb = lane >> 4;
  const int f7 = fr & 7;

  // staging (R2-verified pair): linear dest, pre-swizzled source chunk
  const int sr = t >> 3;
  const int sc = (t & 7) ^ (sr & 7);
  const __bf16* As = A + (size_t)(bm + sr) * K + sc * 8;
  const __bf16* Bs = Bt + (size_t)(bn + sr) * K + sc * 8;
  const int dst0 = t * 8;

  f32x4 acc[4][4] = {};

  auto STG = [&](int s) {
    const int base = (s & 1) * 16384;
    const __bf16* ap = As + (s << 6);
    const __bf16* bp = Bs + (s << 6);
#pragma unroll
    for (int j = 0; j < 4; j++) {
      gload16(ap + (size_t)(j << 5) * K, &lds[base + dst0 + (j << 11)]);
      gload16(bp + (size_t)(j << 5) * K, &lds[base + 8192 + dst0 + (j << 11)]);
    }
  };

  STG(0);
  WAITV(0);
  BARF();

  for (int s = 0; s < nt; s++) {
    if (s + 1 < nt) STG(s + 1);
    const int abase = (s & 1) * 16384 + (wr * 64 + fr) * 64;
    const int bbase = (s & 1) * 16384 + 8192 + (wc * 64 + fr) * 64;
#pragma unroll
    for (int ks = 0; ks < 2; ks++) {
      b16x8 av[4], bv[4];
#pragma unroll
      for (int m = 0; m < 4; m++) {
        const int sw = (((ks << 2) | kb) ^ f7) << 3;
        av[m] = *reinterpret_cast<const b16x8*>(&lds[abase + m * 1024 + sw]);
      }
#pragma unroll
      for (int n = 0; n < 4; n++) {
        const int sw = (((ks << 2) | kb) ^ f7) << 3;
        bv[n] = *reinterpret_cast<const b16x8*>(&lds[bbase + n * 1024 + sw]);
      }
#pragma unroll
      for (int m = 0; m < 4; m++)
#pragma unroll
        for (int n = 0; n < 4; n++)
          acc[m][n] = __builtin_amdgcn_mfma_f32_16x16x32_bf16(av[m], bv[n], acc[m][n], 0, 0, 0);
    }
    WAITV(0);
    BARF();
  }

  const int r0 = kb * 4;
  const int cc = fr;
#pragma unroll
  for (int m = 0; m < 4; m++) {
#pragma unroll
    for (int n = 0; n < 4; n++) {
      const int col = bn + wc * 64 + n * 16 + cc;
#pragma unroll
      for (int r = 0; r < 4; r++) {
        const int row = bm + wr * 64 + m * 16 + r0 + r;
        const float val = acc[m][n][r];
        if constexpr (EPI == 2) {
          const float xg = val + bias[col];
          const float gel = 0.5f * xg * (1.f + erff(xg * 0.70710678118f));
          h0[(size_t)row * N + col] = (__bf16)gel;
        } else {
          const size_t idx = (size_t)row * N + col;
          f0[idx] = f0[idx] + val + bias[col];
        }
      }
    }
  }
}

// ---------------- attention pass 1 ------------------------------------------
__global__ __launch_bounds__(256) void attn_pass1(const __bf16* __restrict__ q,
                                                  const __bf16* __restrict__ k,
                                                  const float* __restrict__ qsum,
                                                  const float* __restrict__ ksum,
                                                  float* __restrict__ si_out,
                                                  float* __restrict__ qkpart) {
  __shared__ float lsQ[512], lsK[512];
  const int t = threadIdx.x, lane = t & 63, wv = t >> 6;
  const int c0 = lane * 8;
  lsQ[t] = 0.f; lsQ[t + 256] = 0.f;
  lsK[t] = 0.f; lsK[t + 256] = 0.f;
  __syncthreads();
  float qs[8], ks[8];
#pragma unroll
  for (int j = 0; j < 8; j++) {
    qs[j] = qsum[c0 + j] + EPSF;
    ks[j] = ksum[c0 + j] + EPSF;
  }
  const int h = lane >> 3;
  float qacc[8] = {}, kacc[8] = {};
#pragma unroll 1
  for (int i = 0; i < 8; i++) {
    const int l = blockIdx.x * 32 + wv * 8 + i;
    const b16x8 q8 = *reinterpret_cast<const b16x8*>(q + (size_t)l * 512 + c0);
    const b16x8 k8 = *reinterpret_cast<const b16x8*>(k + (size_t)l * 512 + c0);
    float qf[8], kf[8];
    float p1 = 0.f, p2 = 0.f;
#pragma unroll
    for (int j = 0; j < 8; j++) {
      qf[j] = (float)q8[j]; kf[j] = (float)k8[j];
      p1 += (qf[j] + EPSF) * ks[j];
      p2 += (kf[j] + EPSF) * qs[j];
    }
    p1 += __shfl_xor(p1, 1); p2 += __shfl_xor(p2, 1);
    p1 += __shfl_xor(p1, 2); p2 += __shfl_xor(p2, 2);
    p1 += __shfl_xor(p1, 4); p2 += __shfl_xor(p2, 4);
    const float siv = 1.f / p1, sov = 1.f / p2;
    if ((lane & 7) == 0) si_out[h * L_SEQ + l] = siv;
#pragma unroll
    for (int j = 0; j < 8; j++) { qacc[j] += qf[j] * siv; kacc[j] += kf[j] * sov; }
  }
#pragma unroll
  for (int j = 0; j < 8; j++) {
    atomicAdd(&lsQ[c0 + j], qacc[j]);
    atomicAdd(&lsK[c0 + j], kacc[j]);
  }
  __syncthreads();
  float* qp = qkpart + (size_t)blockIdx.x * 1024;
  qp[t] = lsQ[t];
  qp[t + 256] = lsQ[t + 256];
  qp[t + 512] = lsK[t];
  qp[t + 768] = lsK[t + 256];
}

__global__ __launch_bounds__(256) void reduce_qk(const float* __restrict__ qkpart,
                                                 float* __restrict__ outv) {
  const int i = blockIdx.x * 256 + threadIdx.x;
  float s = 0.f;
#pragma unroll 4
  for (int b = 0; b < 512; b++) s += qkpart[(size_t)b * 1024 + i];
  outv[i] = s;
}

// ---------------- kv partials (bf16 v) --------------------------------------
__global__ __launch_bounds__(256) void kv_part(const __bf16* __restrict__ k,
                                               const __bf16* __restrict__ v,
                                               const float* __restrict__ qsi,
                                               float* __restrict__ kvpart,
                                               float* __restrict__ separt) {
  const int h = blockIdx.y, bx = blockIdx.x, t = threadIdx.x;
  __shared__ float lsK[64 * 68];
  __shared__ float lsV[64 * 68];
  __shared__ float lsRed[256];
  const int r = t >> 2, cq = (t & 3) * 16;
  float qv[16];
#pragma unroll
  for (int j = 0; j < 16; j++) qv[j] = qsi[h * 64 + cq + j] + EPSF;
  const int d = t & 63, mg = t >> 6;
  f32x4 acc4[4] = {};
  float seloc = 0.f;
#pragma unroll 1
  for (int sc = 0; sc < 4; sc++) {
    const int l = bx * 256 + sc * 64 + r;
    __syncthreads();
    const b16x8 k8a = *reinterpret_cast<const b16x8*>(k + (size_t)l * 512 + h * 64 + cq);
    const b16x8 k8b = *reinterpret_cast<const b16x8*>(k + (size_t)l * 512 + h * 64 + cq + 8);
    const b16x8 v8a = *reinterpret_cast<const b16x8*>(v + (size_t)l * 512 + h * 64 + cq);
    const b16x8 v8b = *reinterpret_cast<const b16x8*>(v + (size_t)l * 512 + h * 64 + cq + 8);
    float kf[16], vf[16];
#pragma unroll
    for (int j = 0; j < 8; j++) {
      kf[j] = (float)k8a[j]; kf[8 + j] = (float)k8b[j];
      vf[j] = (float)v8a[j]; vf[8 + j] = (float)v8b[j];
    }
    float p = 0.f;
#pragma unroll
    for (int j = 0; j < 16; j++) p += (kf[j] + EPSF) * qv[j];
    p += __shfl_xor(p, 1);
    p += __shfl_xor(p, 2);
    p = fminf(fmaxf(p, -1.f), 1.f);
    const float ce = __expf(p);
    if ((t & 3) == 0) seloc += ce;
#pragma unroll
    for (int j = 0; j < 16; j++) {
      lsK[r * 68 + cq + j] = kf[j];
      lsV[r * 68 + cq + j] = vf[j] * ce;
    }
    __syncthreads();
    for (int rr = 0; rr < 64; rr++) {
      const float kd = lsK[rr * 68 + d];
      const f32x4* lv = reinterpret_cast<const f32x4*>(&lsV[rr * 68 + mg * 16]);
#pragma unroll
      for (int jj = 0; jj < 4; jj++) acc4[jj] += lv[jj] * kd;
    }
  }
  float* kp = kvpart + ((size_t)h * 64 + bx) * 4096;
#pragma unroll
  for (int jj = 0; jj < 4; jj++)
    *reinterpret_cast<f32x4*>(&kp[d * 64 + mg * 16 + jj * 4]) = acc4[jj];
  lsRed[t] = ((t & 3) == 0) ? seloc : 0.f;
  __syncthreads();
  for (int s2 = 128; s2 > 0; s2 >>= 1) {
    if (t < s2) lsRed[t] += lsRed[t + s2];
    __syncthreads();
  }
  if (t == 0) separt[h * 64 + bx] = lsRed[0];
}

__global__ __launch_bounds__(256) void kv_reduce(const float* __restrict__ kvpart,
                                                 const float* __restrict__ separt,
                                                 float* __restrict__ kvout,
                                                 float* __restrict__ sumexp) {
  const int h = blockIdx.y, t = threadIdx.x;
  const int i = blockIdx.x * 256 + t;
  float s = 0.f;
#pragma unroll 4
  for (int b = 0; b < 64; b++) s += kvpart[((size_t)h * 64 + b) * 4096 + i];
  kvout[h * 4096 + i] = s;
  if (blockIdx.x == 0 && t < 64) {
    float e = separt[h * 64 + t];
#pragma unroll
    for (int off2 = 32; off2 > 0; off2 >>= 1) e += __shfl_down(e, off2);
    if (t == 0) sumexp[h] = e;
  }
}

// ---------------- o kernel ---------------------------------------------------
__global__ __launch_bounds__(256) void o_kernel(const __bf16* __restrict__ q,
                                                const float* __restrict__ kvin,
                                                const float* __restrict__ si,
                                                const float* __restrict__ kso,
                                                const float* __restrict__ sumexp,
                                                __bf16* __restrict__ o) {
  const int h = blockIdx.y;
  const int l0 = blockIdx.x * 32;
  const int t = threadIdx.x;
  __shared__ float lsKV[64 * 64];
  __shared__ float lsQ[32 * 65];
  __shared__ float lsF[32];
  const float Sfac = (float)L_SEQ / sumexp[h];
#pragma unroll
  for (int j = 0; j < 16; j++) lsKV[t + j * 256] = kvin[h * 4096 + t + j * 256];
  const int r = t >> 3, c8 = (t & 7) * 8;
  float ksov[8];
#pragma unroll
  for (int j = 0; j < 8; j++) ksov[j] = kso[h * 64 + c8 + j] + EPSF;
  const b16x8 q8 = *reinterpret_cast<const b16x8*>(q + (size_t)(l0 + r) * 512 + h * 64 + c8);
  float p = 0.f;
#pragma unroll
  for (int j = 0; j < 8; j++) {
    const float qf = (float)q8[j];
    lsQ[r * 65 + c8 + j] = qf;
    p += (qf + EPSF) * ksov[j];
  }
  p += __shfl_xor(p, 1);
  p += __shfl_xor(p, 2);
  p += __shfl_xor(p, 4);
  if ((t & 7) == 0) lsF[r] = sigmoidf_(p) * si[h * L_SEQ + l0 + r] * Sfac;
  __syncthreads();
  const int m = t & 63, rg = t >> 6;
#pragma unroll 1
  for (int i = 0; i < 8; i++) {
    const int rr = rg + i * 4;
    float a = 0.f;
#pragma unroll
    for (int dd = 0; dd < 64; dd++) a += lsQ[rr * 65 + dd] * lsKV[dd * 64 + m];
    o[(size_t)(l0 + rr) * 512 + h * 64 + m] = (__bf16)(a * lsF[rr]);
  }
}

// ---------------------------------------------------------------------------
extern "C" void kernel_launch(void* const* d_in, const int* in_sizes, int n_in,
                              void* d_out, int out_size, void* d_ws, size_t ws_size,
                              hipStream_t stream) {
  const float* x  = (const float*)d_in[0];
  const float* Wq = (const float*)d_in[1];
  const float* bq = (const float*)d_in[2];
  const float* Wk = (const float*)d_in[3];
  const float* bk = (const float*)d_in[4];
  const float* Wv = (const float*)d_in[5];
  const float* bv = (const float*)d_in[6];
  const float* Wo = (const float*)d_in[7];
  const float* bo = (const float*)d_in[8];
  const float* W1 = (const float*)d_in[9];
  const float* b1 = (const float*)d_in[10];
  const float* W2 = (const float*)d_in[11];
  const float* b2 = (const float*)d_in[12];
  const float* g1 = (const float*)d_in[13];
  const float* be1 = (const float*)d_in[14];
  const float* g2 = (const float*)d_in[15];
  const float* be2 = (const float*)d_in[16];
  float* out = (float*)d_out;

  char* ws = (char*)d_ws;
  size_t off = 0;
  auto alloc = [&](size_t bytes) -> char* {
    char* p = ws + off;
    off += (bytes + 255) & ~(size_t)255;
    return p;
  };

  char* regA = alloc(134217728);
  __bf16* ln1  = (__bf16*)regA;
  __bf16* qb16 = (__bf16*)(regA + 16777216);
  __bf16* kb16 = (__bf16*)(regA + 33554432);
  __bf16* vb16 = (__bf16*)(regA + 50331648);
  __bf16* ob   = (__bf16*)(regA + 83886080);
  __bf16* sa   = (__bf16*)regA;                  // 2 x 16.78 MB bf16 splits
  __bf16* act  = (__bf16*)regA;

  __bf16* ln2 = (__bf16*)alloc((size_t)32768 * 512 * 2);
  __bf16* Wqkvt = (__bf16*)alloc((size_t)1536 * 512 * 2);
  __bf16* Wot = (__bf16*)alloc((size_t)512 * 512 * 2);
  __bf16* W1t = (__bf16*)alloc((size_t)2048 * 512 * 2);
  __bf16* W2t = (__bf16*)alloc((size_t)512 * 2048 * 2);
  float* biascat = (float*)alloc(1536 * 4);
  float* si = (float*)alloc((size_t)8 * L_SEQ * 4);
  float* stats = (float*)alloc(34880 * 4);
  float* qsum = stats;
  float* ksum = stats + 512;
  float* qsi = stats + 1024;
  float* kso = stats + 1536;
  float* sumexp = stats + 2048;
  float* kvbuf = stats + 2112;
  float* kvpart = (float*)alloc((size_t)8 * 64 * 4096 * 4);
  float* separt = (float*)alloc(512 * 4);
  float* qkpart = (float*)alloc((size_t)512 * 1024 * 4);

  prep_k<<<3087, 256, 0, stream>>>(Wq, Wk, Wv, Wo, W1, W2, bq, bk, bv,
                                   Wqkvt, Wot, W1t, W2t, biascat, stats);

  ln_rows<<<L_SEQ, 128, 0, stream>>>(x, g1, be1, ln1);
  gemm128<0, 0><<<1536, 256, 0, stream>>>(ln1, Wqkvt, L_SEQ, 1536, 512,
                                          biascat, (float*)vb16, qb16, kb16, qsum, ksum);

  attn_pass1<<<512, 256, 0, stream>>>(qb16, kb16, qsum, ksum, si, qkpart);
  reduce_qk<<<4, 256, 0, stream>>>(qkpart, qsi);
  kv_part<<<dim3(64, 8), 256, 0, stream>>>(kb16, vb16, qsi, kvpart, separt);
  kv_reduce<<<dim3(16, 8), 256, 0, stream>>>(kvpart, separt, kvbuf, sumexp);
  o_kernel<<<dim3(L_SEQ / 32, 8), 256, 0, stream>>>(qb16, kvbuf, si, kso, sumexp, ob);

  gemm128<1, 1><<<dim3(512, 2), 256, 0, stream>>>(ob, Wot, L_SEQ, 512, 512,
                                                  nullptr, nullptr, sa, nullptr,
                                                  nullptr, nullptr);

  x2ln2_k<<<2 * L_SEQ, 128, 0, stream>>>(x, sa, sa + (size_t)L_SEQ * 512, bo,
                                         g2, be2, out, ln2);

  // MLP via zero-conflict BK=64 kernels
  gemm128b<2><<<4096, 256, 0, stream>>>(ln2, W1t, 2 * L_SEQ, 2048, 512,
                                        b1, nullptr, act);
  gemm128b<3><<<1024, 256, 0, stream>>>(act, W2t, 2 * L_SEQ, 512, 2048,
                                        b2, out, nullptr);
}

// Round 15
// 487.630 us; speedup vs baseline: 1.0986x; 1.0664x over previous
//
#include <hip/hip_runtime.h>
#include <hip/hip_bf16.h>
#include <cstdint>
#include <cstddef>

// ---------------------------------------------------------------------------
// FlowformerLayer: LN1 -> flow-attention(batch0) -> +res -> LN2 -> MLP -> +res
// B=2, L=16384, D=512, H=8, DH=64, F=2048
// Consolidation round: best-measured components only.
//  - All GEMMs: R12 gemm128 (128x128, BK=32, 4 waves, dbuf 32KB, 1 barrier/
//    K-tile, 4 blocks/CU) — fastest measured across the 14-round matrix
//    (phase structure x depth x occupancy x shape x conflicts all null).
//  - sa bf16 (Wo epilogue + x2ln2 read), v bf16 — verified numerics wins.
//  - prep_k single-launch weight prep; slab-reduced attention chain.
// ---------------------------------------------------------------------------

#define L_SEQ 16384
#define EPSF 1e-6f

typedef __bf16 b16x8 __attribute__((ext_vector_type(8)));
typedef __bf16 b16x4 __attribute__((ext_vector_type(4)));
typedef float  f32x4 __attribute__((ext_vector_type(4)));

#define FENCE() asm volatile("" ::: "memory")
#define BARF()  { FENCE(); __builtin_amdgcn_s_barrier(); FENCE(); }
#define WAITV(n) asm volatile("s_waitcnt vmcnt(" #n ")" ::: "memory")

__device__ __forceinline__ void gload16(const void* g, void* l) {
  __builtin_amdgcn_global_load_lds((const __attribute__((address_space(1))) void*)g,
                                   (__attribute__((address_space(3))) void*)l, 16, 0, 0);
}

__device__ __forceinline__ float sigmoidf_(float x) { return 1.f / (1.f + __expf(-x)); }

// ---------------- prep: all weight transposes + biascat + zeroing, 1 launch
__global__ __launch_bounds__(256) void prep_k(const float* __restrict__ Wq,
                                              const float* __restrict__ Wk,
                                              const float* __restrict__ Wv,
                                              const float* __restrict__ Wo,
                                              const float* __restrict__ W1,
                                              const float* __restrict__ W2,
                                              const float* __restrict__ bq,
                                              const float* __restrict__ bk,
                                              const float* __restrict__ bv,
                                              __bf16* __restrict__ Wqkvt,
                                              __bf16* __restrict__ Wot,
                                              __bf16* __restrict__ W1t,
                                              __bf16* __restrict__ W2t,
                                              float* __restrict__ biascat,
                                              float* __restrict__ zstats) {
  const int b = blockIdx.x;
  if (b >= 3072) {
    const int i = (b - 3072) * 256 + threadIdx.x;
    if (i < 1536) biascat[i] = (i < 512) ? bq[i] : (i < 1024) ? bk[i - 512] : bv[i - 1024];
    else if (i < 1536 + 2112) zstats[i - 1536] = 0.f;
    return;
  }
  const float* src;
  __bf16* dst;
  int K, N, bx, by;
  if (b < 256)       { src = Wq; dst = Wqkvt;                      K = 512;  N = 512;  const int r = b;        bx = r & 15; by = r >> 4; }
  else if (b < 512)  { src = Wk; dst = Wqkvt + (size_t)512 * 512;  K = 512;  N = 512;  const int r = b - 256;  bx = r & 15; by = r >> 4; }
  else if (b < 768)  { src = Wv; dst = Wqkvt + (size_t)1024 * 512; K = 512;  N = 512;  const int r = b - 512;  bx = r & 15; by = r >> 4; }
  else if (b < 1024) { src = Wo; dst = Wot;                        K = 512;  N = 512;  const int r = b - 768;  bx = r & 15; by = r >> 4; }
  else if (b < 2048) { src = W1; dst = W1t;                        K = 512;  N = 2048; const int r = b - 1024; bx = r & 63; by = r >> 6; }
  else               { src = W2; dst = W2t;                        K = 2048; N = 512;  const int r = b - 2048; bx = r & 15; by = r >> 4; }
  __shared__ float tile[32][33];
  const int k0 = by * 32, n0 = bx * 32;
  const int tx = threadIdx.x & 31, ty = threadIdx.x >> 5;
#pragma unroll
  for (int i = 0; i < 32; i += 8) tile[ty + i][tx] = src[(size_t)(k0 + ty + i) * N + n0 + tx];
  __syncthreads();
#pragma unroll
  for (int i = 0; i < 32; i += 8)
    dst[(size_t)(n0 + ty + i) * K + k0 + tx] = (__bf16)tile[tx][ty + i];
}

// ---------------- LayerNorm over D=512, one row per block
__global__ __launch_bounds__(128) void ln_rows(const float* __restrict__ x,
                                               const float* __restrict__ g,
                                               const float* __restrict__ be,
                                               __bf16* __restrict__ out) {
  const int row = blockIdx.x, t = threadIdx.x;
  const float4 xv = reinterpret_cast<const float4*>(x + (size_t)row * 512)[t];
  float s = xv.x + xv.y + xv.z + xv.w;
  float s2 = xv.x * xv.x + xv.y * xv.y + xv.z * xv.z + xv.w * xv.w;
#pragma unroll
  for (int off = 32; off > 0; off >>= 1) { s += __shfl_down(s, off); s2 += __shfl_down(s2, off); }
  __shared__ float red[4];
  if ((t & 63) == 0) { red[(t >> 6) * 2] = s; red[(t >> 6) * 2 + 1] = s2; }
  __syncthreads();
  const float S = red[0] + red[2], S2 = red[1] + red[3];
  const float mean = S * (1.f / 512.f);
  const float var = S2 * (1.f / 512.f) - mean * mean;
  const float inv = rsqrtf(var + 1e-5f);
  const float4 gv = reinterpret_cast<const float4*>(g)[t];
  const float4 bv = reinterpret_cast<const float4*>(be)[t];
  b16x4 o;
  o[0] = (__bf16)((xv.x - mean) * inv * gv.x + bv.x);
  o[1] = (__bf16)((xv.y - mean) * inv * gv.y + bv.y);
  o[2] = (__bf16)((xv.z - mean) * inv * gv.z + bv.z);
  o[3] = (__bf16)((xv.w - mean) * inv * gv.w + bv.w);
  reinterpret_cast<b16x4*>(out + (size_t)row * 512)[t] = o;
}

// ---------------- x2 = x + sa0 + sa1 + bo (sa bf16); d_out=x2; ln2=LN(x2)
__global__ __launch_bounds__(128) void x2ln2_k(const float* __restrict__ x,
                                               const __bf16* __restrict__ sa0,
                                               const __bf16* __restrict__ sa1,
                                               const float* __restrict__ bo,
                                               const float* __restrict__ g,
                                               const float* __restrict__ be,
                                               float* __restrict__ xout,
                                               __bf16* __restrict__ lnout) {
  const int row = blockIdx.x, t = threadIdx.x;
  const int l = row & (L_SEQ - 1);
  float4 xv = reinterpret_cast<const float4*>(x + (size_t)row * 512)[t];
  const b16x4 s0 = reinterpret_cast<const b16x4*>(sa0 + (size_t)l * 512)[t];
  const b16x4 s1 = reinterpret_cast<const b16x4*>(sa1 + (size_t)l * 512)[t];
  const float4 bb = reinterpret_cast<const float4*>(bo)[t];
  xv.x += (float)s0[0] + (float)s1[0] + bb.x;
  xv.y += (float)s0[1] + (float)s1[1] + bb.y;
  xv.z += (float)s0[2] + (float)s1[2] + bb.z;
  xv.w += (float)s0[3] + (float)s1[3] + bb.w;
  reinterpret_cast<float4*>(xout + (size_t)row * 512)[t] = xv;
  float s = xv.x + xv.y + xv.z + xv.w;
  float s2 = xv.x * xv.x + xv.y * xv.y + xv.z * xv.z + xv.w * xv.w;
#pragma unroll
  for (int off = 32; off > 0; off >>= 1) { s += __shfl_down(s, off); s2 += __shfl_down(s2, off); }
  __shared__ float red[4];
  if ((t & 63) == 0) { red[(t >> 6) * 2] = s; red[(t >> 6) * 2 + 1] = s2; }
  __syncthreads();
  const float S = red[0] + red[2], S2 = red[1] + red[3];
  const float mean = S * (1.f / 512.f);
  const float var = S2 * (1.f / 512.f) - mean * mean;
  const float inv = rsqrtf(var + 1e-5f);
  const float4 gv = reinterpret_cast<const float4*>(g)[t];
  const float4 bv = reinterpret_cast<const float4*>(be)[t];
  b16x4 o;
  o[0] = (__bf16)((xv.x - mean) * inv * gv.x + bv.x);
  o[1] = (__bf16)((xv.y - mean) * inv * gv.y + bv.y);
  o[2] = (__bf16)((xv.z - mean) * inv * gv.z + bv.z);
  o[3] = (__bf16)((xv.w - mean) * inv * gv.w + bv.w);
  reinterpret_cast<b16x4*>(lnout + (size_t)row * 512)[t] = o;
}

// ---------------- gemm128 (R12 config): all four GEMMs ----------------------
// EPI 0: QKV (+biascat, sigmoid q/k -> bf16 h0/h1 + colsums f1/f2; v -> bf16)
// EPI 1: SA  (val -> bf16 h0, split-K via blockIdx.y)
// EPI 2: GELU(+bias -> bf16 h0, stride N)
// EPI 3: OUT (f0[row,col] += acc + bias)
template <int EPI, int KSPL>
__global__ __launch_bounds__(256, 4) void gemm128(const __bf16* __restrict__ A,
                                                  const __bf16* __restrict__ Bt,
                                                  const int M, const int N, const int K,
                                                  const float* __restrict__ bias,
                                                  float* __restrict__ f0,
                                                  __bf16* __restrict__ h0,
                                                  __bf16* __restrict__ h1,
                                                  float* __restrict__ f1,
                                                  float* __restrict__ f2) {
  __shared__ alignas(16) __bf16 lds[16384];  // 32 KB

  if constexpr (KSPL) {
    const int z = blockIdx.y;
    A += (size_t)z * (K >> 1);
    Bt += (size_t)z * (K >> 1);
    h0 += (size_t)z * ((size_t)M * N);
  }
  const int nt = KSPL ? (K >> 6) : (K >> 5);

  const int nwg = gridDim.x;
  const int orig = blockIdx.x;
  const int cpx = nwg >> 3;
  const int wg = (orig & 7) * cpx + (orig >> 3);
  const int gx = N >> 7;
  const int bm = (wg / gx) << 7;
  const int bn = (wg % gx) << 7;

  const int t = threadIdx.x;
  const int w = t >> 6, lane = t & 63;
  const int wr = w >> 1, wc = w & 1;
  const int fr = lane & 15;
  const int kb = lane >> 4;

  const __bf16* As = A + (size_t)(bm + (t >> 2)) * K + (t & 3) * 8;
  const __bf16* Bs = Bt + (size_t)(bn + (t >> 2)) * K + (t & 3) * 8;

  f32x4 acc[4][4] = {};

  auto STG = [&](int s) {
    const int sel = (s & 1) * 4096;
    const __bf16* ap = As + (s << 5);
    const __bf16* bp = Bs + (s << 5);
    gload16(ap, &lds[sel + t * 8]);
    gload16(ap + (size_t)64 * K, &lds[sel + 2048 + t * 8]);
    gload16(bp, &lds[8192 + sel + t * 8]);
    gload16(bp + (size_t)64 * K, &lds[8192 + sel + 2048 + t * 8]);
  };

  STG(0);
  WAITV(0);
  BARF();

  for (int s = 0; s < nt; s++) {
    if (s + 1 < nt) STG(s + 1);
    const int ab = (s & 1) * 4096 + (wr * 64 + fr) * 32 + kb * 8;
    const int bb2 = 8192 + (s & 1) * 4096 + (wc * 64 + fr) * 32 + kb * 8;
    b16x8 av[4], bv[4];
#pragma unroll
    for (int m = 0; m < 4; m++)
      av[m] = *reinterpret_cast<const b16x8*>(&lds[ab + m * 512]);
#pragma unroll
    for (int n = 0; n < 4; n++)
      bv[n] = *reinterpret_cast<const b16x8*>(&lds[bb2 + n * 512]);
#pragma unroll
    for (int m = 0; m < 4; m++)
#pragma unroll
      for (int n = 0; n < 4; n++)
        acc[m][n] = __builtin_amdgcn_mfma_f32_16x16x32_bf16(av[m], bv[n], acc[m][n], 0, 0, 0);
    WAITV(0);
    BARF();
  }

  const int r0 = kb * 4;
  const int cc = fr;
  if constexpr (EPI == 0) {
    const int which = bn >> 9;  // 0=q, 1=k, 2=v
    float cs[4] = {0.f, 0.f, 0.f, 0.f};
#pragma unroll
    for (int m = 0; m < 4; m++) {
#pragma unroll
      for (int n = 0; n < 4; n++) {
        const int col = bn + wc * 64 + n * 16 + cc;
        const int c2 = col & 511;
#pragma unroll
        for (int r = 0; r < 4; r++) {
          const int row = bm + wr * 64 + m * 16 + r0 + r;
          float val = acc[m][n][r] + bias[col];
          if (which < 2) {
            val = sigmoidf_(val);
            cs[n] += val;
            ((which == 0) ? h0 : h1)[(size_t)row * 512 + c2] = (__bf16)val;
          } else {
            ((__bf16*)f0)[(size_t)row * 512 + c2] = (__bf16)val;  // v bf16
          }
        }
      }
    }
    if (which < 2) {
      float* sums = (which == 0) ? f1 : f2;
#pragma unroll
      for (int n = 0; n < 4; n++) {
        float s = cs[n];
        s += __shfl_xor(s, 16);
        s += __shfl_xor(s, 32);
        if (kb == 0) atomicAdd(&sums[(bn & 511) + wc * 64 + n * 16 + cc], s);
      }
    }
  } else {
#pragma unroll
    for (int m = 0; m < 4; m++) {
#pragma unroll
      for (int n = 0; n < 4; n++) {
        const int col = bn + wc * 64 + n * 16 + cc;
#pragma unroll
        for (int r = 0; r < 4; r++) {
          const int row = bm + wr * 64 + m * 16 + r0 + r;
          const float val = acc[m][n][r];
          if constexpr (EPI == 1) {
            h0[(size_t)row * N + col] = (__bf16)val;           // sa bf16
          } else if constexpr (EPI == 2) {
            const float xg = val + bias[col];
            const float gel = 0.5f * xg * (1.f + erff(xg * 0.70710678118f));
            h0[(size_t)row * N + col] = (__bf16)gel;
          } else {
            const size_t idx = (size_t)row * N + col;
            f0[idx] = f0[idx] + val + bias[col];
          }
        }
      }
    }
  }
}

// ---------------- attention pass 1 ------------------------------------------
__global__ __launch_bounds__(256) void attn_pass1(const __bf16* __restrict__ q,
                                                  const __bf16* __restrict__ k,
                                                  const float* __restrict__ qsum,
                                                  const float* __restrict__ ksum,
                                                  float* __restrict__ si_out,
                                                  float* __restrict__ qkpart) {
  __shared__ float lsQ[512], lsK[512];
  const int t = threadIdx.x, lane = t & 63, wv = t >> 6;
  const int c0 = lane * 8;
  lsQ[t] = 0.f; lsQ[t + 256] = 0.f;
  lsK[t] = 0.f; lsK[t + 256] = 0.f;
  __syncthreads();
  float qs[8], ks[8];
#pragma unroll
  for (int j = 0; j < 8; j++) {
    qs[j] = qsum[c0 + j] + EPSF;
    ks[j] = ksum[c0 + j] + EPSF;
  }
  const int h = lane >> 3;
  float qacc[8] = {}, kacc[8] = {};
#pragma unroll 1
  for (int i = 0; i < 8; i++) {
    const int l = blockIdx.x * 32 + wv * 8 + i;
    const b16x8 q8 = *reinterpret_cast<const b16x8*>(q + (size_t)l * 512 + c0);
    const b16x8 k8 = *reinterpret_cast<const b16x8*>(k + (size_t)l * 512 + c0);
    float qf[8], kf[8];
    float p1 = 0.f, p2 = 0.f;
#pragma unroll
    for (int j = 0; j < 8; j++) {
      qf[j] = (float)q8[j]; kf[j] = (float)k8[j];
      p1 += (qf[j] + EPSF) * ks[j];
      p2 += (kf[j] + EPSF) * qs[j];
    }
    p1 += __shfl_xor(p1, 1); p2 += __shfl_xor(p2, 1);
    p1 += __shfl_xor(p1, 2); p2 += __shfl_xor(p2, 2);
    p1 += __shfl_xor(p1, 4); p2 += __shfl_xor(p2, 4);
    const float siv = 1.f / p1, sov = 1.f / p2;
    if ((lane & 7) == 0) si_out[h * L_SEQ + l] = siv;
#pragma unroll
    for (int j = 0; j < 8; j++) { qacc[j] += qf[j] * siv; kacc[j] += kf[j] * sov; }
  }
#pragma unroll
  for (int j = 0; j < 8; j++) {
    atomicAdd(&lsQ[c0 + j], qacc[j]);
    atomicAdd(&lsK[c0 + j], kacc[j]);
  }
  __syncthreads();
  float* qp = qkpart + (size_t)blockIdx.x * 1024;
  qp[t] = lsQ[t];
  qp[t + 256] = lsQ[t + 256];
  qp[t + 512] = lsK[t];
  qp[t + 768] = lsK[t + 256];
}

__global__ __launch_bounds__(256) void reduce_qk(const float* __restrict__ qkpart,
                                                 float* __restrict__ outv) {
  const int i = blockIdx.x * 256 + threadIdx.x;
  float s = 0.f;
#pragma unroll 4
  for (int b = 0; b < 512; b++) s += qkpart[(size_t)b * 1024 + i];
  outv[i] = s;
}

// ---------------- kv partials (bf16 v) --------------------------------------
__global__ __launch_bounds__(256) void kv_part(const __bf16* __restrict__ k,
                                               const __bf16* __restrict__ v,
                                               const float* __restrict__ qsi,
                                               float* __restrict__ kvpart,
                                               float* __restrict__ separt) {
  const int h = blockIdx.y, bx = blockIdx.x, t = threadIdx.x;
  __shared__ float lsK[64 * 68];
  __shared__ float lsV[64 * 68];
  __shared__ float lsRed[256];
  const int r = t >> 2, cq = (t & 3) * 16;
  float qv[16];
#pragma unroll
  for (int j = 0; j < 16; j++) qv[j] = qsi[h * 64 + cq + j] + EPSF;
  const int d = t & 63, mg = t >> 6;
  f32x4 acc4[4] = {};
  float seloc = 0.f;
#pragma unroll 1
  for (int sc = 0; sc < 4; sc++) {
    const int l = bx * 256 + sc * 64 + r;
    __syncthreads();
    const b16x8 k8a = *reinterpret_cast<const b16x8*>(k + (size_t)l * 512 + h * 64 + cq);
    const b16x8 k8b = *reinterpret_cast<const b16x8*>(k + (size_t)l * 512 + h * 64 + cq + 8);
    const b16x8 v8a = *reinterpret_cast<const b16x8*>(v + (size_t)l * 512 + h * 64 + cq);
    const b16x8 v8b = *reinterpret_cast<const b16x8*>(v + (size_t)l * 512 + h * 64 + cq + 8);
    float kf[16], vf[16];
#pragma unroll
    for (int j = 0; j < 8; j++) {
      kf[j] = (float)k8a[j]; kf[8 + j] = (float)k8b[j];
      vf[j] = (float)v8a[j]; vf[8 + j] = (float)v8b[j];
    }
    float p = 0.f;
#pragma unroll
    for (int j = 0; j < 16; j++) p += (kf[j] + EPSF) * qv[j];
    p += __shfl_xor(p, 1);
    p += __shfl_xor(p, 2);
    p = fminf(fmaxf(p, -1.f), 1.f);
    const float ce = __expf(p);
    if ((t & 3) == 0) seloc += ce;
#pragma unroll
    for (int j = 0; j < 16; j++) {
      lsK[r * 68 + cq + j] = kf[j];
      lsV[r * 68 + cq + j] = vf[j] * ce;
    }
    __syncthreads();
    for (int rr = 0; rr < 64; rr++) {
      const float kd = lsK[rr * 68 + d];
      const f32x4* lv = reinterpret_cast<const f32x4*>(&lsV[rr * 68 + mg * 16]);
#pragma unroll
      for (int jj = 0; jj < 4; jj++) acc4[jj] += lv[jj] * kd;
    }
  }
  float* kp = kvpart + ((size_t)h * 64 + bx) * 4096;
#pragma unroll
  for (int jj = 0; jj < 4; jj++)
    *reinterpret_cast<f32x4*>(&kp[d * 64 + mg * 16 + jj * 4]) = acc4[jj];
  lsRed[t] = ((t & 3) == 0) ? seloc : 0.f;
  __syncthreads();
  for (int s2 = 128; s2 > 0; s2 >>= 1) {
    if (t < s2) lsRed[t] += lsRed[t + s2];
    __syncthreads();
  }
  if (t == 0) separt[h * 64 + bx] = lsRed[0];
}

__global__ __launch_bounds__(256) void kv_reduce(const float* __restrict__ kvpart,
                                                 const float* __restrict__ separt,
                                                 float* __restrict__ kvout,
                                                 float* __restrict__ sumexp) {
  const int h = blockIdx.y, t = threadIdx.x;
  const int i = blockIdx.x * 256 + t;
  float s = 0.f;
#pragma unroll 4
  for (int b = 0; b < 64; b++) s += kvpart[((size_t)h * 64 + b) * 4096 + i];
  kvout[h * 4096 + i] = s;
  if (blockIdx.x == 0 && t < 64) {
    float e = separt[h * 64 + t];
#pragma unroll
    for (int off2 = 32; off2 > 0; off2 >>= 1) e += __shfl_down(e, off2);
    if (t == 0) sumexp[h] = e;
  }
}

// ---------------- o kernel ---------------------------------------------------
__global__ __launch_bounds__(256) void o_kernel(const __bf16* __restrict__ q,
                                                const float* __restrict__ kvin,
                                                const float* __restrict__ si,
                                                const float* __restrict__ kso,
                                                const float* __restrict__ sumexp,
                                                __bf16* __restrict__ o) {
  const int h = blockIdx.y;
  const int l0 = blockIdx.x * 32;
  const int t = threadIdx.x;
  __shared__ float lsKV[64 * 64];
  __shared__ float lsQ[32 * 65];
  __shared__ float lsF[32];
  const float Sfac = (float)L_SEQ / sumexp[h];
#pragma unroll
  for (int j = 0; j < 16; j++) lsKV[t + j * 256] = kvin[h * 4096 + t + j * 256];
  const int r = t >> 3, c8 = (t & 7) * 8;
  float ksov[8];
#pragma unroll
  for (int j = 0; j < 8; j++) ksov[j] = kso[h * 64 + c8 + j] + EPSF;
  const b16x8 q8 = *reinterpret_cast<const b16x8*>(q + (size_t)(l0 + r) * 512 + h * 64 + c8);
  float p = 0.f;
#pragma unroll
  for (int j = 0; j < 8; j++) {
    const float qf = (float)q8[j];
    lsQ[r * 65 + c8 + j] = qf;
    p += (qf + EPSF) * ksov[j];
  }
  p += __shfl_xor(p, 1);
  p += __shfl_xor(p, 2);
  p += __shfl_xor(p, 4);
  if ((t & 7) == 0) lsF[r] = sigmoidf_(p) * si[h * L_SEQ + l0 + r] * Sfac;
  __syncthreads();
  const int m = t & 63, rg = t >> 6;
#pragma unroll 1
  for (int i = 0; i < 8; i++) {
    const int rr = rg + i * 4;
    float a = 0.f;
#pragma unroll
    for (int dd = 0; dd < 64; dd++) a += lsQ[rr * 65 + dd] * lsKV[dd * 64 + m];
    o[(size_t)(l0 + rr) * 512 + h * 64 + m] = (__bf16)(a * lsF[rr]);
  }
}

// ---------------------------------------------------------------------------
extern "C" void kernel_launch(void* const* d_in, const int* in_sizes, int n_in,
                              void* d_out, int out_size, void* d_ws, size_t ws_size,
                              hipStream_t stream) {
  const float* x  = (const float*)d_in[0];
  const float* Wq = (const float*)d_in[1];
  const float* bq = (const float*)d_in[2];
  const float* Wk = (const float*)d_in[3];
  const float* bk = (const float*)d_in[4];
  const float* Wv = (const float*)d_in[5];
  const float* bv = (const float*)d_in[6];
  const float* Wo = (const float*)d_in[7];
  const float* bo = (const float*)d_in[8];
  const float* W1 = (const float*)d_in[9];
  const float* b1 = (const float*)d_in[10];
  const float* W2 = (const float*)d_in[11];
  const float* b2 = (const float*)d_in[12];
  const float* g1 = (const float*)d_in[13];
  const float* be1 = (const float*)d_in[14];
  const float* g2 = (const float*)d_in[15];
  const float* be2 = (const float*)d_in[16];
  float* out = (float*)d_out;

  char* ws = (char*)d_ws;
  size_t off = 0;
  auto alloc = [&](size_t bytes) -> char* {
    char* p = ws + off;
    off += (bytes + 255) & ~(size_t)255;
    return p;
  };

  char* regA = alloc(134217728);
  __bf16* ln1  = (__bf16*)regA;
  __bf16* qb16 = (__bf16*)(regA + 16777216);
  __bf16* kb16 = (__bf16*)(regA + 33554432);
  __bf16* vb16 = (__bf16*)(regA + 50331648);
  __bf16* ob   = (__bf16*)(regA + 83886080);
  __bf16* sa   = (__bf16*)regA;                  // 2 x 16.78 MB bf16 splits
  __bf16* act  = (__bf16*)regA;

  __bf16* ln2 = (__bf16*)alloc((size_t)32768 * 512 * 2);
  __bf16* Wqkvt = (__bf16*)alloc((size_t)1536 * 512 * 2);
  __bf16* Wot = (__bf16*)alloc((size_t)512 * 512 * 2);
  __bf16* W1t = (__bf16*)alloc((size_t)2048 * 512 * 2);
  __bf16* W2t = (__bf16*)alloc((size_t)512 * 2048 * 2);
  float* biascat = (float*)alloc(1536 * 4);
  float* si = (float*)alloc((size_t)8 * L_SEQ * 4);
  float* stats = (float*)alloc(34880 * 4);
  float* qsum = stats;
  float* ksum = stats + 512;
  float* qsi = stats + 1024;
  float* kso = stats + 1536;
  float* sumexp = stats + 2048;
  float* kvbuf = stats + 2112;
  float* kvpart = (float*)alloc((size_t)8 * 64 * 4096 * 4);
  float* separt = (float*)alloc(512 * 4);
  float* qkpart = (float*)alloc((size_t)512 * 1024 * 4);

  prep_k<<<3087, 256, 0, stream>>>(Wq, Wk, Wv, Wo, W1, W2, bq, bk, bv,
                                   Wqkvt, Wot, W1t, W2t, biascat, stats);

  ln_rows<<<L_SEQ, 128, 0, stream>>>(x, g1, be1, ln1);
  gemm128<0, 0><<<1536, 256, 0, stream>>>(ln1, Wqkvt, L_SEQ, 1536, 512,
                                          biascat, (float*)vb16, qb16, kb16, qsum, ksum);

  attn_pass1<<<512, 256, 0, stream>>>(qb16, kb16, qsum, ksum, si, qkpart);
  reduce_qk<<<4, 256, 0, stream>>>(qkpart, qsi);
  kv_part<<<dim3(64, 8), 256, 0, stream>>>(kb16, vb16, qsi, kvpart, separt);
  kv_reduce<<<dim3(16, 8), 256, 0, stream>>>(kvpart, separt, kvbuf, sumexp);
  o_kernel<<<dim3(L_SEQ / 32, 8), 256, 0, stream>>>(qb16, kvbuf, si, kso, sumexp, ob);

  gemm128<1, 1><<<dim3(512, 2), 256, 0, stream>>>(ob, Wot, L_SEQ, 512, 512,
                                                  nullptr, nullptr, sa, nullptr,
                                                  nullptr, nullptr);

  x2ln2_k<<<2 * L_SEQ, 128, 0, stream>>>(x, sa, sa + (size_t)L_SEQ * 512, bo,
                                         g2, be2, out, ln2);

  gemm128<2, 0><<<4096, 256, 0, stream>>>(ln2, W1t, 2 * L_SEQ, 2048, 512,
                                          b1, nullptr, act, nullptr, nullptr, nullptr);
  gemm128<3, 0><<<1024, 256, 0, stream>>>(act, W2t, 2 * L_SEQ, 512, 2048,
                                          b2, out, nullptr, nullptr, nullptr, nullptr);
}